// Round 5
// baseline (464.439 us; speedup 1.0000x reference)
//
#include <hip/hip_runtime.h>
#include <hip/hip_fp16.h>
#include <stdint.h>

#define B_  8
#define S_  2048
#define D_  512
#define K_  4096
#define N_  (B_ * S_)          // 16384 rows
#define NCB (K_ / 128)         // 32 code-blocks
#define NKB (D_ / 32)          // 16 k-blocks

typedef _Float16 half8  __attribute__((ext_vector_type(8)));
typedef float    floatx4 __attribute__((ext_vector_type(4)));

// ---- workspace layout (bytes) ----
#define OFF_PV   0                                  // [N_][32] float  (2 MB)
#define OFF_PI   (OFF_PV + (size_t)N_ * NCB * 4)    // [N_][32] int    (2 MB)
#define OFF_EN   (OFF_PI + (size_t)N_ * NCB * 4)    // enorm [K_]
#define OFF_ZN   (OFF_EN + K_ * 4)                  // znorm [N_]
#define OFF_CNT  (OFF_ZN + N_ * 4)                  // counts [K_]
#define OFF_BL   (OFF_CNT + K_ * 4)                 // blockLoss [4096]
#define OFF_DONE (OFF_BL + 4096 * 4)                // done counter [1]
#define OFF_ZH   (OFF_DONE + 256)                   // zh packed [NKB][N_][32] f16 (16 MB)
#define OFF_ZL   (OFF_ZH + (size_t)N_ * D_ * 2)     // zl packed (16 MB)
#define OFF_EH   (OFF_ZL + (size_t)N_ * D_ * 2)     // eh packed [NKB][K_][32] (4 MB)
#define OFF_EL   (OFF_EH + (size_t)K_ * D_ * 2)     // el packed (4 MB)

// async 16B global->LDS DMA; lds dst must be wave-uniform base + lane*16
__device__ __forceinline__ void load_lds16(const _Float16* g, _Float16* l) {
    __builtin_amdgcn_global_load_lds(
        (const __attribute__((address_space(1))) unsigned int*)(uintptr_t)g,
        (__attribute__((address_space(3))) unsigned int*)(uintptr_t)l,
        16, 0, 0);
}

// ---------------- kernel 1: fused prep ----------------
// One wave per row (z rows then cb rows):
//  (a) row norm, reduction order BIT-IDENTICAL to rounds 2-4 (preserves the
//      fp32 distance lattice), (b) fp32->fp16 hi/lo split, packed K-block-major
//      with XOR chunk swizzle (codebook scaled by 64, exact), (c) zero counts+done.
__global__ __launch_bounds__(256)
void vq_prep_kernel(const float* __restrict__ z, const float* __restrict__ cb,
                    _Float16* __restrict__ zh, _Float16* __restrict__ zl,
                    _Float16* __restrict__ eh, _Float16* __restrict__ el,
                    float* __restrict__ znorm, float* __restrict__ enorm,
                    int* __restrict__ counts, int* __restrict__ done) {
    const int t = threadIdx.x;
    if (blockIdx.x < 16) counts[blockIdx.x * 256 + t] = 0;
    if (blockIdx.x == 16 && t == 0) done[0] = 0;

    const size_t u = (size_t)blockIdx.x * 256 + t;
    const int c   = (int)(u & 63);     // lane / chunk id (8 consecutive k)
    const int row = (int)(u >> 6);
    const bool isZ = row < N_;
    const int n = isZ ? row : row - N_;
    const float* r = (isZ ? z : cb) + (size_t)n * D_;

    // (a) norm — identical order to rounds 2-4
    float s = 0.f;
    for (int j = c; j < D_; j += 64) { float v = r[j]; s += v * v; }
    #pragma unroll
    for (int m = 1; m < 64; m <<= 1) s += __shfl_xor(s, m, 64);
    if (c == 0) { if (isZ) znorm[n] = s; else enorm[n] = s; }

    // (b) split
    const float scale = isZ ? 1.0f : 64.0f;
    const float4 v0 = *(const float4*)(r + c * 8);
    const float4 v1 = *(const float4*)(r + c * 8 + 4);
    float a[8] = {v0.x, v0.y, v0.z, v0.w, v1.x, v1.y, v1.z, v1.w};
    half8 h, lo;
    #pragma unroll
    for (int j = 0; j < 8; j++) {
        const float x = a[j] * scale;
        const _Float16 hh = (_Float16)x;
        h[j]  = hh;
        lo[j] = (_Float16)(x - (float)hh);
    }
    const int kb = c >> 2, qd = c & 3;
    const int sw = qd ^ ((n >> 1) & 3);
    const size_t rows = isZ ? (size_t)N_ : (size_t)K_;
    const size_t off = (size_t)kb * rows * 32 + (size_t)n * 32 + (size_t)(sw << 3);
    if (isZ) {
        *(half8*)(zh + off) = h;
        *(half8*)(zl + off) = lo;
    } else {
        *(half8*)(eh + off) = h;
        *(half8*)(el + off) = lo;
    }
}

// ---------------- kernel 2: fused distance GEMM + per-tile argmin ----------------
// d[m][c] = fp32(fp32(znorm[m] + enorm[c]) - 2*dot) on np's fp32 lattice.
// dot = (zh*eh' + zh*el' + zl*eh') * 2^-6, e' = 64e = eh' + el'. (lo*lo dropped.)
// Pipeline: ONE barrier per k-step. A (z hi/lo) double-buffered in LDS via
// global_load_lds issued a full MFMA-phase before its consuming barrier drain;
// B (eh/el, L2-resident) read per-step as coalesced global->VGPR fragment loads.
__global__ __launch_bounds__(256, 3)
void vq_dist_kernel(const _Float16* __restrict__ zh, const _Float16* __restrict__ zl,
                    const _Float16* __restrict__ eh, const _Float16* __restrict__ el,
                    const float* __restrict__ enorm, const float* __restrict__ znorm,
                    float* __restrict__ pV, int* __restrict__ pI) {
    __shared__ _Float16 sAh[2][4096], sAl[2][4096];   // 32 KB A double-buffer
    __shared__ float sE[128], sZn[128];
    __shared__ float candV[2][128];
    __shared__ int   candI[2][128];

    const int t  = threadIdx.x;
    const int c0 = blockIdx.x * 128;   // x = c-fast: eh/el + current z-tile L2-resident
    const int m0 = blockIdx.y * 128;

    if (t < 128) { sE[t] = enorm[c0 + t]; sZn[t] = znorm[m0 + t]; }

    const int lane = t & 63, wid = t >> 6;
    const int wr = wid & 1, wc = wid >> 1;
    const int qd = lane >> 4, nl = lane & 15;
    const int sw8 = (qd ^ ((nl >> 1) & 3)) << 3;

    // A staging: waves 0/1 -> zh chunks 0-3/4-7; waves 2/3 -> zl chunks 0-3/4-7
    const _Float16* gsrc = ((wid < 2) ? zh : zl) + (size_t)m0 * 32
                         + (size_t)((wid & 1) * 4) * 512 + (size_t)lane * 8;
    _Float16* ldst[2] = {
        ((wid < 2) ? sAh[0] : sAl[0]) + (wid & 1) * 4 * 512,
        ((wid < 2) ? sAh[1] : sAl[1]) + (wid & 1) * 4 * 512
    };
    const size_t strideA = (size_t)N_ * 32;
    const size_t strideB = (size_t)K_ * 32;
    const _Float16* behk = eh + (size_t)c0 * 32;
    const _Float16* belk = el + (size_t)c0 * 32;

    floatx4 acc[4][4];
    #pragma unroll
    for (int i = 0; i < 4; i++)
        #pragma unroll
        for (int j = 0; j < 4; j++) acc[i][j] = (floatx4)0.f;

    // prologue: stage kb=0 into buffer 0
    #pragma unroll
    for (int g = 0; g < 4; g++)
        load_lds16(gsrc + g * 512, ldst[0] + g * 512);

    for (int kb = 0; kb < NKB; kb++) {
        __syncthreads();   // drains own vmcnt: A(kb) landed; all waves done with buf (kb+1)&1

        // B fragments for this step: coalesced 1KB wave-loads from L2
        half8 b_h[4], b_l[4];
        #pragma unroll
        for (int s = 0; s < 4; s++) {
            const int br = wc * 64 + s * 16 + nl;
            b_h[s] = *(const half8*)(behk + (size_t)kb * strideB + br * 32 + sw8);
            b_l[s] = *(const half8*)(belk + (size_t)kb * strideB + br * 32 + sw8);
        }
        // prefetch A(kb+1) into the other buffer; drained only at the NEXT barrier
        if (kb + 1 < NKB) {
            const _Float16* gk = gsrc + (size_t)(kb + 1) * strideA;
            _Float16* ld = ldst[(kb + 1) & 1];
            #pragma unroll
            for (int g = 0; g < 4; g++)
                load_lds16(gk + g * 512, ld + g * 512);
        }
        // A fragments from current buffer
        const _Float16* ah = sAh[kb & 1];
        const _Float16* al = sAl[kb & 1];
        half8 a_h[4], a_l[4];
        #pragma unroll
        for (int s = 0; s < 4; s++) {
            const int ar = wr * 64 + s * 16 + nl;
            a_h[s] = *(const half8*)&ah[ar * 32 + sw8];
            a_l[s] = *(const half8*)&al[ar * 32 + sw8];
        }
        #pragma unroll
        for (int i = 0; i < 4; i++)
            #pragma unroll
            for (int j = 0; j < 4; j++) {
                acc[i][j] = __builtin_amdgcn_mfma_f32_16x16x32_f16(a_h[i], b_h[j], acc[i][j], 0, 0, 0);
                acc[i][j] = __builtin_amdgcn_mfma_f32_16x16x32_f16(a_h[i], b_l[j], acc[i][j], 0, 0, 0);
                acc[i][j] = __builtin_amdgcn_mfma_f32_16x16x32_f16(a_l[i], b_h[j], acc[i][j], 0, 0, 0);
            }
    }

    // epilogue: identical rounding sequence to rounds 2-4 (np's fp32 lattice)
    #pragma unroll
    for (int sm = 0; sm < 4; sm++) {
        #pragma unroll
        for (int reg = 0; reg < 4; reg++) {
            const int rm = wr * 64 + sm * 16 + qd * 4 + reg;
            const float zn = sZn[rm];
            float bv = 1e30f; int bi = 0x7fffffff;
            #pragma unroll
            for (int sn = 0; sn < 4; sn++) {
                const int cl = wc * 64 + sn * 16 + nl;
                const float dot = acc[sm][sn][reg] * 0.015625f;  // /64, exact
                const float s2  = zn + sE[cl];                   // rounds once
                const float v   = s2 - 2.0f * dot;               // rounds once
                const int ci = c0 + cl;
                if (v < bv || (v == bv && ci < bi)) { bv = v; bi = ci; }
            }
            #pragma unroll
            for (int msk = 1; msk <= 8; msk <<= 1) {
                const float ov = __shfl_xor(bv, msk, 64);
                const int   oi = __shfl_xor(bi, msk, 64);
                if (ov < bv || (ov == bv && oi < bi)) { bv = ov; bi = oi; }
            }
            if (nl == 0) { candV[wc][rm] = bv; candI[wc][rm] = bi; }
        }
    }
    __syncthreads();
    if (t < 128) {
        float v0 = candV[0][t]; int i0 = candI[0][t];
        const float v1 = candV[1][t]; const int i1 = candI[1][t];
        if (v1 < v0 || (v1 == v0 && i1 < i0)) { v0 = v1; i0 = i1; }
        pV[(size_t)(m0 + t) * NCB + blockIdx.x] = v0;
        pI[(size_t)(m0 + t) * NCB + blockIdx.x] = i0;
    }
}

// ---------------- kernel 3: final argmin + gather + loss + histogram + scalars ----------------
// Last-block-done pattern fuses the old vq_final_kernel (saves one dispatch).
__global__ __launch_bounds__(256)
void vq_gather_kernel(const float* __restrict__ z, const float* __restrict__ cb,
                      const float* __restrict__ pV, const int* __restrict__ pI,
                      float* __restrict__ out_zq, float* __restrict__ out_idx,
                      int* __restrict__ counts, float* __restrict__ blockLoss,
                      int* __restrict__ done,
                      float* __restrict__ out_loss, float* __restrict__ out_ppl) {
    const int lane = threadIdx.x & 63, wid = threadIdx.x >> 6;
    const int m = blockIdx.x * 4 + wid;

    float v = 1e30f; int idx = 0x7fffffff;
    if (lane < NCB) { v = pV[(size_t)m * NCB + lane]; idx = pI[(size_t)m * NCB + lane]; }
    #pragma unroll
    for (int msk = 1; msk <= 16; msk <<= 1) {
        const float ov = __shfl_xor(v, msk, 64);
        const int   oi = __shfl_xor(idx, msk, 64);
        if (ov < v || (ov == v && oi < idx)) { v = ov; idx = oi; }
    }
    idx = __shfl(idx, 0, 64);

    const float4* qrow = (const float4*)(cb + (size_t)idx * D_);
    const float4* zrow = (const float4*)(z  + (size_t)m   * D_);
    float4*       orow = (float4*)(out_zq + (size_t)m * D_);
    float lsum = 0.f;
    #pragma unroll
    for (int i = 0; i < 2; i++) {
        const int j = lane + i * 64;
        const float4 q  = qrow[j];
        const float4 zv = zrow[j];
        float4 o;
        o.x = zv.x + (q.x - zv.x); o.y = zv.y + (q.y - zv.y);
        o.z = zv.z + (q.z - zv.z); o.w = zv.w + (q.w - zv.w);
        orow[j] = o;
        const float dx = zv.x - q.x, dy = zv.y - q.y, dz = zv.z - q.z, dw = zv.w - q.w;
        lsum += dx * dx + dy * dy + dz * dz + dw * dw;
    }
    #pragma unroll
    for (int msk = 1; msk < 64; msk <<= 1) lsum += __shfl_xor(lsum, msk, 64);

    if (lane == 0) {
        out_idx[m] = (float)idx;
        atomicAdd(&counts[idx], 1);
    }
    __shared__ float wl[4];
    __shared__ int amLast;
    if (lane == 0) wl[wid] = lsum;
    __syncthreads();   // also drains each wave's vmcnt (stores + atomics complete)
    if (threadIdx.x == 0) {
        blockLoss[blockIdx.x] = wl[0] + wl[1] + wl[2] + wl[3];
        __threadfence();   // device-scope release of this block's writes
        amLast = (atomicAdd(done, 1) == (int)gridDim.x - 1);
    }
    __syncthreads();
    if (amLast) {
        __threadfence();
        __shared__ float sl[256], se[256];
        const int t = threadIdx.x;
        float ls = 0.f, es = 0.f;
        for (int i = t; i < N_ / 4; i += 256)
            ls += __hip_atomic_load(&blockLoss[i], __ATOMIC_RELAXED, __HIP_MEMORY_SCOPE_AGENT);
        for (int k = t; k < K_; k += 256) {
            const int c = __hip_atomic_load(&counts[k], __ATOMIC_RELAXED, __HIP_MEMORY_SCOPE_AGENT);
            const float p = (float)c / (float)N_;
            es += p * logf(p + 1e-10f);
        }
        sl[t] = ls; se[t] = es;
        __syncthreads();
        for (int s = 128; s > 0; s >>= 1) {
            if (t < s) { sl[t] += sl[t + s]; se[t] += se[t + s]; }
            __syncthreads();
        }
        if (t == 0) {
            out_loss[0] = 0.25f * (sl[0] / (float)((size_t)N_ * D_));
            out_ppl[0]  = expf(-se[0]);
        }
    }
}

extern "C" void kernel_launch(void* const* d_in, const int* in_sizes, int n_in,
                              void* d_out, int out_size, void* d_ws, size_t ws_size,
                              hipStream_t stream) {
    const float* z  = (const float*)d_in[0];
    const float* cb = (const float*)d_in[1];
    float* out = (float*)d_out;

    char* ws = (char*)d_ws;
    float*    pV        = (float*)   (ws + OFF_PV);
    int*      pI        = (int*)     (ws + OFF_PI);
    float*    enorm     = (float*)   (ws + OFF_EN);
    float*    znorm     = (float*)   (ws + OFF_ZN);
    int*      counts    = (int*)     (ws + OFF_CNT);
    float*    blockLoss = (float*)   (ws + OFF_BL);
    int*      done      = (int*)     (ws + OFF_DONE);
    _Float16* zh        = (_Float16*)(ws + OFF_ZH);
    _Float16* zl        = (_Float16*)(ws + OFF_ZL);
    _Float16* eh        = (_Float16*)(ws + OFF_EH);
    _Float16* el        = (_Float16*)(ws + OFF_EL);

    float* out_zq   = out;                         // [N_*D_]
    float* out_loss = out + (size_t)N_ * D_;       // [1]
    float* out_idx  = out_loss + 1;                // [N_]
    float* out_ppl  = out_idx + N_;                // [1]

    vq_prep_kernel<<<(N_ + K_) * 64 / 256, 256, 0, stream>>>(z, cb, zh, zl, eh, el,
                                                             znorm, enorm, counts, done);

    dim3 grid(K_ / 128, N_ / 128);   // x = c-block fast: eh/el + z-tile L2-resident
    vq_dist_kernel<<<grid, 256, 0, stream>>>(zh, zl, eh, el, enorm, znorm, pV, pI);

    vq_gather_kernel<<<N_ / 4, 256, 0, stream>>>(z, cb, pV, pI, out_zq, out_idx,
                                                 counts, blockLoss, done,
                                                 out_loss, out_ppl);
}

// Round 6
// 249.767 us; speedup vs baseline: 1.8595x; 1.8595x over previous
//
#include <hip/hip_runtime.h>
#include <hip/hip_fp16.h>
#include <stdint.h>

#define B_  8
#define S_  2048
#define D_  512
#define K_  4096
#define N_  (B_ * S_)          // 16384 rows
#define NCB (K_ / 128)         // 32 code-blocks
#define NKB (D_ / 32)          // 16 k-blocks
#define MARGIN 4e-3f           // ~16 sigma of the 1-term approx error on d

typedef _Float16 half8  __attribute__((ext_vector_type(8)));
typedef float    floatx4 __attribute__((ext_vector_type(4)));

// ---- workspace layout (bytes) ----
#define OFF_PV0  0                                   // [N_][32] float (2 MB)
#define OFF_PI0  (OFF_PV0 + (size_t)N_ * NCB * 4)    // [N_][32] int
#define OFF_PV1  (OFF_PI0 + (size_t)N_ * NCB * 4)    // [N_][32] float (2nd-best)
#define OFF_PI1  (OFF_PV1 + (size_t)N_ * NCB * 4)    // [N_][32] int
#define OFF_EN   (OFF_PI1 + (size_t)N_ * NCB * 4)    // enorm [K_]
#define OFF_ZN   (OFF_EN + K_ * 4)                   // znorm [N_]
#define OFF_CNT  (OFF_ZN + N_ * 4)                   // counts [K_]
#define OFF_BL   (OFF_CNT + K_ * 4)                  // blockLoss [4096]
#define OFF_ZH   (OFF_BL + 4096 * 4)                 // zh packed [NKB][N_][32] f16 (16 MB)
#define OFF_EH   (OFF_ZH + (size_t)N_ * D_ * 2)      // eh packed [NKB][K_][32] f16 (4 MB)

__device__ __forceinline__ bool lexlt(float va, int ia, float vb, int ib) {
    return va < vb || (va == vb && ia < ib);
}

// async 16B global->LDS DMA; lds dst must be wave-uniform base + lane*16
__device__ __forceinline__ void load_lds16(const _Float16* g, _Float16* l) {
    __builtin_amdgcn_global_load_lds(
        (const __attribute__((address_space(1))) unsigned int*)(uintptr_t)g,
        (__attribute__((address_space(3))) unsigned int*)(uintptr_t)l,
        16, 0, 0);
}

// ---------------- kernel 1: fused prep ----------------
// One wave per row (z rows then cb rows):
//  (a) row norm, reduction order BIT-IDENTICAL to rounds 2-5 (preserves the
//      fp32 distance lattice); (b) fp32->fp16 HI split only, packed
//      K-block-major with XOR chunk swizzle (codebook scaled by 64, exact);
//  (c) zero the histogram counts.
__global__ __launch_bounds__(256)
void vq_prep_kernel(const float* __restrict__ z, const float* __restrict__ cb,
                    _Float16* __restrict__ zh, _Float16* __restrict__ eh,
                    float* __restrict__ znorm, float* __restrict__ enorm,
                    int* __restrict__ counts) {
    const int t = threadIdx.x;
    if (blockIdx.x < 16) counts[blockIdx.x * 256 + t] = 0;

    const size_t u = (size_t)blockIdx.x * 256 + t;
    const int c   = (int)(u & 63);     // lane / chunk id (8 consecutive k)
    const int row = (int)(u >> 6);
    const bool isZ = row < N_;
    const int n = isZ ? row : row - N_;
    const float* r = (isZ ? z : cb) + (size_t)n * D_;

    // (a) norm — identical order to rounds 2-5
    float s = 0.f;
    for (int j = c; j < D_; j += 64) { float v = r[j]; s += v * v; }
    #pragma unroll
    for (int m = 1; m < 64; m <<= 1) s += __shfl_xor(s, m, 64);
    if (c == 0) { if (isZ) znorm[n] = s; else enorm[n] = s; }

    // (b) hi split
    const float scale = isZ ? 1.0f : 64.0f;
    const float4 v0 = *(const float4*)(r + c * 8);
    const float4 v1 = *(const float4*)(r + c * 8 + 4);
    float a[8] = {v0.x, v0.y, v0.z, v0.w, v1.x, v1.y, v1.z, v1.w};
    half8 h;
    #pragma unroll
    for (int j = 0; j < 8; j++) h[j] = (_Float16)(a[j] * scale);
    const int kb = c >> 2, qd = c & 3;
    const int sw = qd ^ ((n >> 1) & 3);
    const size_t rows = isZ ? (size_t)N_ : (size_t)K_;
    const size_t off = (size_t)kb * rows * 32 + (size_t)n * 32 + (size_t)(sw << 3);
    *(half8*)((isZ ? zh : eh) + off) = h;
}

// ---------------- kernel 2: approx distance GEMM + per-tile top-2 ----------------
// v[m][c] = (znorm[m] + enorm[c]) - 2*(zh.eh')/64  — SELECTION metric only.
// Missing terms (zl.e + zh.el'/64 + lo.lo) have sigma ~2.4e-4 on v; phase 2
// re-evaluates every candidate within MARGIN on the exact fp32 lattice.
// Top-2 per 128-code block so same-block near-ties are never lost.
__global__ __launch_bounds__(256, 4)
void vq_dist_kernel(const _Float16* __restrict__ zh, const _Float16* __restrict__ eh,
                    const float* __restrict__ enorm, const float* __restrict__ znorm,
                    float* __restrict__ pV0, int* __restrict__ pI0,
                    float* __restrict__ pV1, int* __restrict__ pI1) {
    __shared__ _Float16 sA[2][4096];           // 16 KB zh double-buffer
    __shared__ float sE[128], sZn[128];
    __shared__ float cV0[2][128], cV1[2][128];
    __shared__ int   cI0[2][128], cI1[2][128];

    const int t  = threadIdx.x;
    const int c0 = blockIdx.x * 128;   // x = c-fast: 4MB eh L2-resident
    const int m0 = blockIdx.y * 128;

    if (t < 128) { sE[t] = enorm[c0 + t]; sZn[t] = znorm[m0 + t]; }

    const int lane = t & 63, wid = t >> 6;
    const int wr = wid & 1, wc = wid >> 1;
    const int qd = lane >> 4, nl = lane & 15;
    const int sw8 = (qd ^ ((nl >> 1) & 3)) << 3;

    // A staging: wave w stages chunks 2w, 2w+1 (2 x 1KB wave-loads / buffer)
    const _Float16* gsrc = zh + (size_t)m0 * 32 + (size_t)(wid * 2) * 512 + (size_t)lane * 8;
    const size_t strideA = (size_t)N_ * 32;
    const size_t strideB = (size_t)K_ * 32;
    const _Float16* behk = eh + (size_t)c0 * 32;

    floatx4 acc[4][4];
    #pragma unroll
    for (int i = 0; i < 4; i++)
        #pragma unroll
        for (int j = 0; j < 4; j++) acc[i][j] = (floatx4)0.f;

    // prologue: stage kb=0 into buffer 0
    #pragma unroll
    for (int g = 0; g < 2; g++)
        load_lds16(gsrc + g * 512, sA[0] + wid * 2 * 512 + g * 512);

    for (int kb = 0; kb < NKB; kb++) {
        __syncthreads();   // drains vmcnt: A(kb) landed; buf (kb+1)&1 free

        // B fragments: coalesced global loads from L2-resident eh
        half8 b_h[4];
        #pragma unroll
        for (int s = 0; s < 4; s++) {
            const int br = wc * 64 + s * 16 + nl;
            b_h[s] = *(const half8*)(behk + (size_t)kb * strideB + br * 32 + sw8);
        }
        // prefetch A(kb+1); drained only at the NEXT barrier
        if (kb + 1 < NKB) {
            const _Float16* gk = gsrc + (size_t)(kb + 1) * strideA;
            _Float16* ld = sA[(kb + 1) & 1] + wid * 2 * 512;
            #pragma unroll
            for (int g = 0; g < 2; g++)
                load_lds16(gk + g * 512, ld + g * 512);
        }
        const _Float16* ah = sA[kb & 1];
        half8 a_h[4];
        #pragma unroll
        for (int s = 0; s < 4; s++) {
            const int ar = wr * 64 + s * 16 + nl;
            a_h[s] = *(const half8*)&ah[ar * 32 + sw8];
        }
        #pragma unroll
        for (int i = 0; i < 4; i++)
            #pragma unroll
            for (int j = 0; j < 4; j++)
                acc[i][j] = __builtin_amdgcn_mfma_f32_16x16x32_f16(a_h[i], b_h[j], acc[i][j], 0, 0, 0);
    }

    // epilogue: per-row top-2 (lexicographic) over this 128-code block
    #pragma unroll
    for (int sm = 0; sm < 4; sm++) {
        #pragma unroll
        for (int reg = 0; reg < 4; reg++) {
            const int rm = wr * 64 + sm * 16 + qd * 4 + reg;
            const float zn = sZn[rm];
            float v0 = 1e30f, v1 = 1e30f; int i0 = 0x7fffffff, i1 = 0x7fffffff;
            #pragma unroll
            for (int sn = 0; sn < 4; sn++) {
                const int cl = wc * 64 + sn * 16 + nl;
                const float dot = acc[sm][sn][reg] * 0.015625f;  // /64, exact
                const float v   = (zn + sE[cl]) - 2.0f * dot;
                const int ci = c0 + cl;
                if (lexlt(v, ci, v0, i0)) { v1 = v0; i1 = i0; v0 = v; i0 = ci; }
                else if (lexlt(v, ci, v1, i1)) { v1 = v; i1 = ci; }
            }
            #pragma unroll
            for (int msk = 1; msk <= 8; msk <<= 1) {
                const float w0 = __shfl_xor(v0, msk, 64);
                const int   j0 = __shfl_xor(i0, msk, 64);
                const float w1 = __shfl_xor(v1, msk, 64);
                const int   j1 = __shfl_xor(i1, msk, 64);
                if (lexlt(w0, j0, v0, i0)) {
                    if (lexlt(v0, i0, w1, j1)) { v1 = v0; i1 = i0; } else { v1 = w1; i1 = j1; }
                    v0 = w0; i0 = j0;
                } else if (lexlt(w0, j0, v1, i1)) { v1 = w0; i1 = j0; }
            }
            if (nl == 0) { cV0[wc][rm] = v0; cI0[wc][rm] = i0; cV1[wc][rm] = v1; cI1[wc][rm] = i1; }
        }
    }
    __syncthreads();
    if (t < 128) {
        float v0 = cV0[0][t], v1 = cV1[0][t];
        int   i0 = cI0[0][t], i1 = cI1[0][t];
        const float w0 = cV0[1][t], w1 = cV1[1][t];
        const int   j0 = cI0[1][t], j1 = cI1[1][t];
        if (lexlt(w0, j0, v0, i0)) {
            if (lexlt(v0, i0, w1, j1)) { v1 = v0; i1 = i0; } else { v1 = w1; i1 = j1; }
            v0 = w0; i0 = j0;
        } else if (lexlt(w0, j0, v1, i1)) { v1 = w0; i1 = j0; }
        const size_t o = (size_t)(m0 + t) * NCB + blockIdx.x;
        pV0[o] = v0; pI0[o] = i0; pV1[o] = v1; pI1[o] = i1;
    }
}

// ---------------- kernel 3: refine + gather + loss partials + histogram ----------------
__global__ __launch_bounds__(256)
void vq_gather_kernel(const float* __restrict__ z, const float* __restrict__ cb,
                      const float* __restrict__ znorm, const float* __restrict__ enorm,
                      const float* __restrict__ pV0, const int* __restrict__ pI0,
                      const float* __restrict__ pV1, const int* __restrict__ pI1,
                      float* __restrict__ out_zq, float* __restrict__ out_idx,
                      int* __restrict__ counts, float* __restrict__ blockLoss) {
    const int lane = threadIdx.x & 63, wid = threadIdx.x >> 6;
    const int m = blockIdx.x * 4 + wid;

    float v0 = 1e30f, v1 = 1e30f; int i0 = 0x7fffffff, i1 = 0x7fffffff;
    if (lane < NCB) {
        const size_t o = (size_t)m * NCB + lane;
        v0 = pV0[o]; i0 = pI0[o]; v1 = pV1[o]; i1 = pI1[o];
    }
    // global approx min (lexicographic)
    float gv = v0; int gi = i0;
    #pragma unroll
    for (int msk = 1; msk < 64; msk <<= 1) {
        const float ov = __shfl_xor(gv, msk, 64);
        const int   oi = __shfl_xor(gi, msk, 64);
        if (lexlt(ov, oi, gv, gi)) { gv = ov; gi = oi; }
    }
    // margin set
    const bool f0 = (lane < NCB) && (v0 <= gv + MARGIN);
    const bool f1 = (lane < NCB) && (v1 <= gv + MARGIN);
    unsigned long long b0 = __ballot(f0), b1 = __ballot(f1);
    int idx = gi;
    if (__popcll(b0) + __popcll(b1) > 1) {
        // exact fp32-lattice distance for each candidate: d = fp32(fp32(zn+en) - 2*dot)
        const float zn = znorm[m];
        const float* zrow = z + (size_t)m * D_;
        float bestd = 1e30f; int besti = 0x7fffffff;
        for (int slot = 0; slot < 2; slot++) {
            unsigned long long bm = slot ? b1 : b0;
            while (bm) {
                const int l = (int)__builtin_ctzll(bm); bm &= bm - 1;
                const int cand = __shfl(slot ? i1 : i0, l, 64);
                const float* crow = cb + (size_t)cand * D_;
                float s = 0.f;
                #pragma unroll
                for (int j = 0; j < 8; j++)
                    s += zrow[lane * 8 + j] * crow[lane * 8 + j];
                #pragma unroll
                for (int msk = 1; msk < 64; msk <<= 1) s += __shfl_xor(s, msk, 64);
                const float d = (zn + enorm[cand]) - 2.0f * s;
                if (lexlt(d, cand, bestd, besti)) { bestd = d; besti = cand; }
            }
        }
        idx = besti;
    }

    const float4* qrow = (const float4*)(cb + (size_t)idx * D_);
    const float4* zrow4 = (const float4*)(z + (size_t)m * D_);
    float4*       orow = (float4*)(out_zq + (size_t)m * D_);
    float lsum = 0.f;
    #pragma unroll
    for (int i = 0; i < 2; i++) {
        const int j = lane + i * 64;
        const float4 q  = qrow[j];
        const float4 zv = zrow4[j];
        float4 o;
        o.x = zv.x + (q.x - zv.x); o.y = zv.y + (q.y - zv.y);
        o.z = zv.z + (q.z - zv.z); o.w = zv.w + (q.w - zv.w);
        orow[j] = o;
        const float dx = zv.x - q.x, dy = zv.y - q.y, dz = zv.z - q.z, dw = zv.w - q.w;
        lsum += dx * dx + dy * dy + dz * dz + dw * dw;
    }
    #pragma unroll
    for (int msk = 1; msk < 64; msk <<= 1) lsum += __shfl_xor(lsum, msk, 64);

    if (lane == 0) {
        out_idx[m] = (float)idx;
        atomicAdd(&counts[idx], 1);
    }
    __shared__ float wl[4];
    if (lane == 0) wl[wid] = lsum;
    __syncthreads();
    if (threadIdx.x == 0) blockLoss[blockIdx.x] = wl[0] + wl[1] + wl[2] + wl[3];
}

// ---------------- kernel 4: scalars (loss, perplexity) ----------------
__global__ void vq_final_kernel(const int* __restrict__ counts,
                                const float* __restrict__ blockLoss,
                                float* __restrict__ out_loss, float* __restrict__ out_ppl) {
    __shared__ float sl[256], se[256];
    const int t = threadIdx.x;
    float ls = 0.f, es = 0.f;
    for (int i = t; i < N_ / 4; i += 256) ls += blockLoss[i];
    for (int k = t; k < K_; k += 256) {
        const float p = (float)counts[k] / (float)N_;
        es += p * logf(p + 1e-10f);
    }
    sl[t] = ls; se[t] = es;
    __syncthreads();
    for (int s = 128; s > 0; s >>= 1) {
        if (t < s) { sl[t] += sl[t + s]; se[t] += se[t + s]; }
        __syncthreads();
    }
    if (t == 0) {
        out_loss[0] = 0.25f * (sl[0] / (float)((size_t)N_ * D_));
        out_ppl[0]  = expf(-se[0]);
    }
}

extern "C" void kernel_launch(void* const* d_in, const int* in_sizes, int n_in,
                              void* d_out, int out_size, void* d_ws, size_t ws_size,
                              hipStream_t stream) {
    const float* z  = (const float*)d_in[0];
    const float* cb = (const float*)d_in[1];
    float* out = (float*)d_out;

    char* ws = (char*)d_ws;
    float*    pV0       = (float*)   (ws + OFF_PV0);
    int*      pI0       = (int*)     (ws + OFF_PI0);
    float*    pV1       = (float*)   (ws + OFF_PV1);
    int*      pI1       = (int*)     (ws + OFF_PI1);
    float*    enorm     = (float*)   (ws + OFF_EN);
    float*    znorm     = (float*)   (ws + OFF_ZN);
    int*      counts    = (int*)     (ws + OFF_CNT);
    float*    blockLoss = (float*)   (ws + OFF_BL);
    _Float16* zh        = (_Float16*)(ws + OFF_ZH);
    _Float16* eh        = (_Float16*)(ws + OFF_EH);

    float* out_zq   = out;                         // [N_*D_]
    float* out_loss = out + (size_t)N_ * D_;       // [1]
    float* out_idx  = out_loss + 1;                // [N_]
    float* out_ppl  = out_idx + N_;                // [1]

    vq_prep_kernel<<<(N_ + K_) * 64 / 256, 256, 0, stream>>>(z, cb, zh, eh,
                                                             znorm, enorm, counts);

    dim3 grid(K_ / 128, N_ / 128);   // x = c-block fast: eh L2-resident
    vq_dist_kernel<<<grid, 256, 0, stream>>>(zh, eh, enorm, znorm, pV0, pI0, pV1, pI1);

    vq_gather_kernel<<<N_ / 4, 256, 0, stream>>>(z, cb, znorm, enorm,
                                                 pV0, pI0, pV1, pI1,
                                                 out_zq, out_idx, counts, blockLoss);

    vq_final_kernel<<<1, 256, 0, stream>>>(counts, blockLoss, out_loss, out_ppl);
}

// Round 7
// 244.029 us; speedup vs baseline: 1.9032x; 1.0235x over previous
//
#include <hip/hip_runtime.h>
#include <hip/hip_fp16.h>
#include <stdint.h>

#define B_  8
#define S_  2048
#define D_  512
#define K_  4096
#define N_  (B_ * S_)          // 16384 rows
#define NCB (K_ / 128)         // 32 code-blocks
#define NKB (D_ / 16)          // unused
#define NKB32 (D_ / 32)        // 16 k-blocks
#define MARGIN 0.014f          // 2*eps(6sigma approx) + 127*ulp(512) key quantization

typedef _Float16 half8  __attribute__((ext_vector_type(8)));
typedef float    floatx4 __attribute__((ext_vector_type(4)));

// ---- workspace layout (bytes) ----
#define OFF_PK   0                                   // [N_][32] uint2 packed top-2 (4 MB)
#define OFF_EN   (OFF_PK + (size_t)N_ * NCB * 8)     // enorm [K_]
#define OFF_ZN   (OFF_EN + K_ * 4)                   // znorm [N_]
#define OFF_CNT  (OFF_ZN + N_ * 4)                   // counts [K_]
#define OFF_BL   (OFF_CNT + K_ * 4)                  // blockLoss [4096]
#define OFF_DONE (OFF_BL + 4096 * 4)                 // done counter
#define OFF_ZH   (OFF_DONE + 256)                    // zh packed [16][N_][32] f16 (16 MB)
#define OFF_EH   (OFF_ZH + (size_t)N_ * D_ * 2)      // eh packed [16][K_][32] f16 (4 MB)

__device__ __forceinline__ uint32_t umin32(uint32_t a, uint32_t b) { return a < b ? a : b; }
__device__ __forceinline__ uint32_t umax32(uint32_t a, uint32_t b) { return a > b ? a : b; }
__device__ __forceinline__ bool lexlt(float va, int ia, float vb, int ib) {
    return va < vb || (va == vb && ia < ib);
}

// async 16B global->LDS DMA; lds dst must be wave-uniform base + lane*16
__device__ __forceinline__ void load_lds16(const _Float16* g, _Float16* l) {
    __builtin_amdgcn_global_load_lds(
        (const __attribute__((address_space(1))) unsigned int*)(uintptr_t)g,
        (__attribute__((address_space(3))) unsigned int*)(uintptr_t)l,
        16, 0, 0);
}

// ---------------- kernel 1: fused prep ----------------
//  (a) row norms (order BIT-IDENTICAL to rounds 2-6 -> preserves fp32 lattice),
//  (b) fp32->fp16 hi split, packed K-block-major + XOR chunk swizzle
//      (codebook scaled by 64, exact), (c) zero counts/done, blockLoss sentinel -1.
__global__ __launch_bounds__(256)
void vq_prep_kernel(const float* __restrict__ z, const float* __restrict__ cb,
                    _Float16* __restrict__ zh, _Float16* __restrict__ eh,
                    float* __restrict__ znorm, float* __restrict__ enorm,
                    int* __restrict__ counts, float* __restrict__ blockLoss,
                    int* __restrict__ done) {
    const int t = threadIdx.x;
    if (blockIdx.x < 16) counts[blockIdx.x * 256 + t] = 0;
    else if (blockIdx.x == 16 && t == 0) done[0] = 0;
    if (blockIdx.x >= 17 && blockIdx.x < 33) blockLoss[(blockIdx.x - 17) * 256 + t] = -1.0f;

    const size_t u = (size_t)blockIdx.x * 256 + t;
    const int c   = (int)(u & 63);     // lane / chunk id (8 consecutive k)
    const int row = (int)(u >> 6);
    const bool isZ = row < N_;
    const int n = isZ ? row : row - N_;
    const float* r = (isZ ? z : cb) + (size_t)n * D_;

    // (a) norm — identical order to rounds 2-6
    float s = 0.f;
    for (int j = c; j < D_; j += 64) { float v = r[j]; s += v * v; }
    #pragma unroll
    for (int m = 1; m < 64; m <<= 1) s += __shfl_xor(s, m, 64);
    if (c == 0) { if (isZ) znorm[n] = s; else enorm[n] = s; }

    // (b) hi split
    const float scale = isZ ? 1.0f : 64.0f;
    const float4 v0 = *(const float4*)(r + c * 8);
    const float4 v1 = *(const float4*)(r + c * 8 + 4);
    float a[8] = {v0.x, v0.y, v0.z, v0.w, v1.x, v1.y, v1.z, v1.w};
    half8 h;
    #pragma unroll
    for (int j = 0; j < 8; j++) h[j] = (_Float16)(a[j] * scale);
    const int kb = c >> 2, qd = c & 3;
    const int sw = qd ^ ((n >> 1) & 3);
    const size_t rows = isZ ? (size_t)N_ : (size_t)K_;
    const size_t off = (size_t)kb * rows * 32 + (size_t)n * 32 + (size_t)(sw << 3);
    *(half8*)((isZ ? zh : eh) + off) = h;
}

// ---------------- kernel 2: approx distance GEMM + per-tile packed top-2 ----------------
// v[m][c] = (znorm+enorm) - 2*(zh.eh')/64 — SELECTION metric; candidates within
// MARGIN re-evaluated exactly in gather. Key = (bits(v) & ~0x7F) | col7 -> u32
// compare == (quantized value, col) lexicographic. Top-2 kept per 128-code block.
__global__ __launch_bounds__(256, 4)
void vq_dist_kernel(const _Float16* __restrict__ zh, const _Float16* __restrict__ eh,
                    const float* __restrict__ enorm, const float* __restrict__ znorm,
                    uint2* __restrict__ pK) {
    __shared__ _Float16 sA[2][4096];           // 16 KB zh double-buffer
    __shared__ float sE[128], sZn[128];
    __shared__ uint2 cK[2][128];

    const int t  = threadIdx.x;
    const int c0 = blockIdx.x * 128;   // x = c-fast: 4MB eh L2-resident
    const int m0 = blockIdx.y * 128;

    if (t < 128) { sE[t] = enorm[c0 + t]; sZn[t] = znorm[m0 + t]; }

    const int lane = t & 63, wid = t >> 6;
    const int wr = wid & 1, wc = wid >> 1;
    const int qd = lane >> 4, nl = lane & 15;
    const int sw8 = (qd ^ ((nl >> 1) & 3)) << 3;

    // A staging: wave w stages chunks 2w, 2w+1 (2 x 1KB wave-loads / buffer)
    const _Float16* gsrc = zh + (size_t)m0 * 32 + (size_t)(wid * 2) * 512 + (size_t)lane * 8;
    const size_t strideA = (size_t)N_ * 32;
    const size_t strideB = (size_t)K_ * 32;
    // single B pointer; fragments at imm offsets s*512 halves (1KB apart)
    const _Float16* bptr = eh + (size_t)c0 * 32 + (size_t)((wc * 64 + nl) * 32 + sw8);
    // A LDS fragment bases (byte-level handled by compiler)
    const int aoff = (wr * 64 + nl) * 32 + sw8;

    floatx4 acc[4][4];
    #pragma unroll
    for (int i = 0; i < 4; i++)
        #pragma unroll
        for (int j = 0; j < 4; j++) acc[i][j] = (floatx4)0.f;

    // prologue: stage kb=0 into buffer 0
    #pragma unroll
    for (int g = 0; g < 2; g++)
        load_lds16(gsrc + g * 512, sA[0] + wid * 2 * 512 + g * 512);

    for (int kb = 0; kb < NKB32; kb++) {
        __syncthreads();   // drains vmcnt: A(kb) landed; buf (kb+1)&1 free

        half8 b_h[4];
        #pragma unroll
        for (int s = 0; s < 4; s++)
            b_h[s] = *(const half8*)(bptr + s * 512);
        if (kb + 1 < NKB32) {
            const _Float16* gk = gsrc + (size_t)(kb + 1) * strideA;
            _Float16* ld = sA[(kb + 1) & 1] + wid * 2 * 512;
            #pragma unroll
            for (int g = 0; g < 2; g++)
                load_lds16(gk + g * 512, ld + g * 512);
        }
        const _Float16* ah = sA[kb & 1] + aoff;
        half8 a_h[4];
        #pragma unroll
        for (int s = 0; s < 4; s++)
            a_h[s] = *(const half8*)(ah + s * 512);
        #pragma unroll
        for (int i = 0; i < 4; i++)
            #pragma unroll
            for (int j = 0; j < 4; j++)
                acc[i][j] = __builtin_amdgcn_mfma_f32_16x16x32_f16(a_h[i], b_h[j], acc[i][j], 0, 0, 0);
        bptr += strideB;
    }

    // epilogue: packed-u32 top-2 per row over this 128-code block
    uint32_t colc[4]; float se4[4];
    #pragma unroll
    for (int sn = 0; sn < 4; sn++) {
        const int cl = wc * 64 + sn * 16 + nl;
        colc[sn] = (uint32_t)cl;          // 7-bit block-local col
        se4[sn]  = sE[cl];
    }
    #pragma unroll
    for (int sm = 0; sm < 4; sm++) {
        #pragma unroll
        for (int reg = 0; reg < 4; reg++) {
            const int rm = wr * 64 + sm * 16 + qd * 4 + reg;
            const float zn = sZn[rm];
            uint32_t k0 = 0xFFFFFFFFu, k1 = 0xFFFFFFFFu;
            #pragma unroll
            for (int sn = 0; sn < 4; sn++) {
                // v = (zn+en) - 2*(acc/64) = fma(acc, -2^-5, s2); product exact either way
                const float v = fmaf(acc[sm][sn][reg], -0.03125f, zn + se4[sn]);
                const uint32_t key = (__float_as_uint(v) & 0xFFFFFF80u) | colc[sn];
                const uint32_t t1 = umax32(k0, key);
                k1 = umin32(k1, t1);
                k0 = umin32(k0, key);
            }
            #pragma unroll
            for (int msk = 1; msk <= 8; msk <<= 1) {
                const uint32_t o0 = (uint32_t)__shfl_xor((int)k0, msk, 64);
                const uint32_t o1 = (uint32_t)__shfl_xor((int)k1, msk, 64);
                const uint32_t n0 = umin32(k0, o0);
                k1 = umin32(umax32(k0, o0), umin32(k1, o1));
                k0 = n0;
            }
            if (nl == 0) { cK[wc][rm].x = k0; cK[wc][rm].y = k1; }
        }
    }
    __syncthreads();
    if (t < 128) {
        const uint2 a = cK[0][t], b = cK[1][t];
        uint2 r;
        r.x = umin32(a.x, b.x);
        r.y = umin32(umax32(a.x, b.x), umin32(a.y, b.y));
        pK[(size_t)(m0 + t) * NCB + blockIdx.x] = r;
    }
}

// ---------------- kernel 3: refine + gather + loss + histogram + fused scalars ----------------
// Finalizer fusion WITHOUT fences: blockLoss via relaxed agent atomic store,
// election via relaxed done counter, completion by VALUE polling
// (sum(counts)==N_ and all blockLoss >= 0; prep wrote -1 sentinels).
__global__ __launch_bounds__(256)
void vq_gather_kernel(const float* __restrict__ z, const float* __restrict__ cb,
                      const float* __restrict__ znorm, const float* __restrict__ enorm,
                      const uint2* __restrict__ pK,
                      float* __restrict__ out_zq, float* __restrict__ out_idx,
                      int* __restrict__ counts, float* __restrict__ blockLoss,
                      int* __restrict__ done,
                      float* __restrict__ out_loss, float* __restrict__ out_ppl) {
    const int lane = threadIdx.x & 63, wid = threadIdx.x >> 6;
    const int m = blockIdx.x * 4 + wid;

    uint32_t k0 = 0xFFFFFFFFu, k1 = 0xFFFFFFFFu;
    if (lane < NCB) {
        const uint2 kk = pK[(size_t)m * NCB + lane];
        k0 = kk.x; k1 = kk.y;
    }
    uint32_t g = k0;
    #pragma unroll
    for (int msk = 1; msk < 64; msk <<= 1) {
        const uint32_t o = (uint32_t)__shfl_xor((int)g, msk, 64);
        g = umin32(g, o);
    }
    const float gvf = __uint_as_float(g & 0xFFFFFF80u) + MARGIN;
    const bool f0 = (lane < NCB) && (__uint_as_float(k0 & 0xFFFFFF80u) <= gvf);
    const bool f1 = (lane < NCB) && (__uint_as_float(k1 & 0xFFFFFF80u) <= gvf);
    const unsigned long long b0 = __ballot(f0), b1 = __ballot(f1);
    int idx;
    if (__popcll(b0) + __popcll(b1) <= 1) {
        const unsigned long long bw = __ballot(k0 == g);
        idx = (int)__builtin_ctzll(bw) * 128 + (int)(g & 0x7Fu);
    } else {
        // exact fp32-lattice distance per candidate: d = fp32(fp32(zn+en) - 2*dot)
        const float zn = znorm[m];
        const float* zrow = z + (size_t)m * D_;
        float bestd = 1e30f; int besti = 0x7fffffff;
        #pragma unroll
        for (int slot = 0; slot < 2; slot++) {
            unsigned long long bm = slot ? b1 : b0;
            while (bm) {
                const int l = (int)__builtin_ctzll(bm); bm &= bm - 1;
                const uint32_t kx = (uint32_t)__shfl((int)(slot ? k1 : k0), l, 64);
                const int cand = l * 128 + (int)(kx & 0x7Fu);
                const float* crow = cb + (size_t)cand * D_;
                float s = 0.f;
                #pragma unroll
                for (int j = 0; j < 8; j++)
                    s += zrow[lane * 8 + j] * crow[lane * 8 + j];
                #pragma unroll
                for (int msk = 1; msk < 64; msk <<= 1) s += __shfl_xor(s, msk, 64);
                const float d = (zn + enorm[cand]) - 2.0f * s;
                if (lexlt(d, cand, bestd, besti)) { bestd = d; besti = cand; }
            }
        }
        idx = besti;
    }

    const float4* qrow  = (const float4*)(cb + (size_t)idx * D_);
    const float4* zrow4 = (const float4*)(z + (size_t)m * D_);
    float4*       orow  = (float4*)(out_zq + (size_t)m * D_);
    float lsum = 0.f;
    #pragma unroll
    for (int i = 0; i < 2; i++) {
        const int j = lane + i * 64;
        const float4 q  = qrow[j];
        const float4 zv = zrow4[j];
        float4 o;
        o.x = zv.x + (q.x - zv.x); o.y = zv.y + (q.y - zv.y);
        o.z = zv.z + (q.z - zv.z); o.w = zv.w + (q.w - zv.w);
        orow[j] = o;
        const float dx = zv.x - q.x, dy = zv.y - q.y, dz = zv.z - q.z, dw = zv.w - q.w;
        lsum += dx * dx + dy * dy + dz * dz + dw * dw;
    }
    #pragma unroll
    for (int msk = 1; msk < 64; msk <<= 1) lsum += __shfl_xor(lsum, msk, 64);

    if (lane == 0) {
        out_idx[m] = (float)idx;
        atomicAdd(&counts[idx], 1);
    }
    __shared__ float wl[4];
    __shared__ int amLast;
    if (lane == 0) wl[wid] = lsum;
    __syncthreads();
    if (threadIdx.x == 0) {
        const float bl = wl[0] + wl[1] + wl[2] + wl[3];
        __hip_atomic_store(&blockLoss[blockIdx.x], bl, __ATOMIC_RELAXED, __HIP_MEMORY_SCOPE_AGENT);
        const int prev = __hip_atomic_fetch_add(done, 1, __ATOMIC_RELAXED, __HIP_MEMORY_SCOPE_AGENT);
        amLast = (prev == (int)gridDim.x - 1);
    }
    __syncthreads();
    if (!amLast) return;

    // ---- finalizer: poll by value, then scalars ----
    const int t = threadIdx.x;
    __shared__ float sl[256], se[256];
    __shared__ int si[256], sok[256];
    __shared__ int goodFlag;
    for (;;) {
        float ls = 0.f, es = 0.f; int tot = 0, ok = 1;
        for (int i = t; i < N_ / 4; i += 256) {
            const float b = __hip_atomic_load(&blockLoss[i], __ATOMIC_RELAXED, __HIP_MEMORY_SCOPE_AGENT);
            if (b >= 0.f) ls += b; else ok = 0;
        }
        for (int k = t; k < K_; k += 256) {
            const int c = __hip_atomic_load(&counts[k], __ATOMIC_RELAXED, __HIP_MEMORY_SCOPE_AGENT);
            tot += c;
            const float p = (float)c / (float)N_;
            es += p * logf(p + 1e-10f);
        }
        sl[t] = ls; se[t] = es; si[t] = tot; sok[t] = ok;
        __syncthreads();
        for (int s = 128; s > 0; s >>= 1) {
            if (t < s) { sl[t] += sl[t + s]; se[t] += se[t + s]; si[t] += si[t + s]; sok[t] &= sok[t + s]; }
            __syncthreads();
        }
        if (t == 0) goodFlag = (si[0] == N_ && sok[0]);
        __syncthreads();
        if (goodFlag) {
            if (t == 0) {
                out_loss[0] = 0.25f * (sl[0] / (float)((size_t)N_ * D_));
                out_ppl[0]  = expf(-se[0]);
            }
            return;
        }
        __syncthreads();
    }
}

extern "C" void kernel_launch(void* const* d_in, const int* in_sizes, int n_in,
                              void* d_out, int out_size, void* d_ws, size_t ws_size,
                              hipStream_t stream) {
    const float* z  = (const float*)d_in[0];
    const float* cb = (const float*)d_in[1];
    float* out = (float*)d_out;

    char* ws = (char*)d_ws;
    uint2*    pK        = (uint2*)   (ws + OFF_PK);
    float*    enorm     = (float*)   (ws + OFF_EN);
    float*    znorm     = (float*)   (ws + OFF_ZN);
    int*      counts    = (int*)     (ws + OFF_CNT);
    float*    blockLoss = (float*)   (ws + OFF_BL);
    int*      done      = (int*)     (ws + OFF_DONE);
    _Float16* zh        = (_Float16*)(ws + OFF_ZH);
    _Float16* eh        = (_Float16*)(ws + OFF_EH);

    float* out_zq   = out;                         // [N_*D_]
    float* out_loss = out + (size_t)N_ * D_;       // [1]
    float* out_idx  = out_loss + 1;                // [N_]
    float* out_ppl  = out_idx + N_;                // [1]

    vq_prep_kernel<<<(N_ + K_) * 64 / 256, 256, 0, stream>>>(z, cb, zh, eh,
                                                             znorm, enorm, counts,
                                                             blockLoss, done);

    dim3 grid(K_ / 128, N_ / 128);   // x = c-block fast: eh L2-resident
    vq_dist_kernel<<<grid, 256, 0, stream>>>(zh, eh, enorm, znorm, pK);

    vq_gather_kernel<<<N_ / 4, 256, 0, stream>>>(z, cb, znorm, enorm, pK,
                                                 out_zq, out_idx, counts, blockLoss,
                                                 done, out_loss, out_ppl);
}

// Round 8
// 202.721 us; speedup vs baseline: 2.2910x; 1.2038x over previous
//
#include <hip/hip_runtime.h>
#include <hip/hip_fp16.h>
#include <stdint.h>

#define B_  8
#define S_  2048
#define D_  512
#define K_  4096
#define N_  (B_ * S_)          // 16384 rows
#define NCB (K_ / 128)         // 32 code-blocks
#define NKB32 (D_ / 32)        // 16 k-blocks
#define MARGIN 0.014f          // 6sigma approx err + 127*ulp(512) key quantization

typedef _Float16 half8  __attribute__((ext_vector_type(8)));
typedef float    floatx4 __attribute__((ext_vector_type(4)));

// ---- workspace layout (bytes) ----
#define OFF_PK   0                                   // [N_][32] uint2 packed top-2 (4 MB)
#define OFF_EN   (OFF_PK + (size_t)N_ * NCB * 8)     // enorm [K_]
#define OFF_ZN   (OFF_EN + K_ * 4)                   // znorm [N_]
#define OFF_CNT  (OFF_ZN + N_ * 4)                   // counts [K_]
#define OFF_BL   (OFF_CNT + K_ * 4)                  // blockLoss [4096]
#define OFF_ZH   (OFF_BL + 4096 * 4)                 // zh packed [16][N_][32] f16 (16 MB)
#define OFF_EH   (OFF_ZH + (size_t)N_ * D_ * 2)      // eh packed [16][K_][32] f16 (4 MB)

__device__ __forceinline__ uint32_t umin32(uint32_t a, uint32_t b) { return a < b ? a : b; }
__device__ __forceinline__ uint32_t umax32(uint32_t a, uint32_t b) { return a > b ? a : b; }
__device__ __forceinline__ bool lexlt(float va, int ia, float vb, int ib) {
    return va < vb || (va == vb && ia < ib);
}

// async 16B global->LDS DMA; lds dst must be wave-uniform base + lane*16
__device__ __forceinline__ void load_lds16(const _Float16* g, _Float16* l) {
    __builtin_amdgcn_global_load_lds(
        (const __attribute__((address_space(1))) unsigned int*)(uintptr_t)g,
        (__attribute__((address_space(3))) unsigned int*)(uintptr_t)l,
        16, 0, 0);
}

// ---------------- kernel 1: fused prep ----------------
//  (a) row norms (order BIT-IDENTICAL to rounds 2-7 -> preserves fp32 lattice),
//  (b) fp32->fp16 hi split, packed K-block-major + XOR chunk swizzle
//      (codebook scaled by 64, exact), (c) zero the histogram counts.
__global__ __launch_bounds__(256)
void vq_prep_kernel(const float* __restrict__ z, const float* __restrict__ cb,
                    _Float16* __restrict__ zh, _Float16* __restrict__ eh,
                    float* __restrict__ znorm, float* __restrict__ enorm,
                    int* __restrict__ counts) {
    const int t = threadIdx.x;
    if (blockIdx.x < 16) counts[blockIdx.x * 256 + t] = 0;

    const size_t u = (size_t)blockIdx.x * 256 + t;
    const int c   = (int)(u & 63);     // lane / chunk id (8 consecutive k)
    const int row = (int)(u >> 6);
    const bool isZ = row < N_;
    const int n = isZ ? row : row - N_;
    const float* r = (isZ ? z : cb) + (size_t)n * D_;

    // (a) norm — identical order to rounds 2-7
    float s = 0.f;
    for (int j = c; j < D_; j += 64) { float v = r[j]; s += v * v; }
    #pragma unroll
    for (int m = 1; m < 64; m <<= 1) s += __shfl_xor(s, m, 64);
    if (c == 0) { if (isZ) znorm[n] = s; else enorm[n] = s; }

    // (b) hi split
    const float scale = isZ ? 1.0f : 64.0f;
    const float4 v0 = *(const float4*)(r + c * 8);
    const float4 v1 = *(const float4*)(r + c * 8 + 4);
    float a[8] = {v0.x, v0.y, v0.z, v0.w, v1.x, v1.y, v1.z, v1.w};
    half8 h;
    #pragma unroll
    for (int j = 0; j < 8; j++) h[j] = (_Float16)(a[j] * scale);
    const int kb = c >> 2, qd = c & 3;
    const int sw = qd ^ ((n >> 1) & 3);
    const size_t rows = isZ ? (size_t)N_ : (size_t)K_;
    const size_t off = (size_t)kb * rows * 32 + (size_t)n * 32 + (size_t)(sw << 3);
    *(half8*)((isZ ? zh : eh) + off) = h;
}

// ---------------- kernel 2: approx distance GEMM + per-tile packed top-2 ----------------
// (byte-identical hot loop to round 7 — measured 90.7 us, MfmaUtil 33%)
__global__ __launch_bounds__(256, 4)
void vq_dist_kernel(const _Float16* __restrict__ zh, const _Float16* __restrict__ eh,
                    const float* __restrict__ enorm, const float* __restrict__ znorm,
                    uint2* __restrict__ pK) {
    __shared__ _Float16 sA[2][4096];           // 16 KB zh double-buffer
    __shared__ float sE[128], sZn[128];
    __shared__ uint2 cK[2][128];

    const int t  = threadIdx.x;
    const int c0 = blockIdx.x * 128;   // x = c-fast: 4MB eh L2-resident
    const int m0 = blockIdx.y * 128;

    if (t < 128) { sE[t] = enorm[c0 + t]; sZn[t] = znorm[m0 + t]; }

    const int lane = t & 63, wid = t >> 6;
    const int wr = wid & 1, wc = wid >> 1;
    const int qd = lane >> 4, nl = lane & 15;
    const int sw8 = (qd ^ ((nl >> 1) & 3)) << 3;

    const _Float16* gsrc = zh + (size_t)m0 * 32 + (size_t)(wid * 2) * 512 + (size_t)lane * 8;
    const size_t strideA = (size_t)N_ * 32;
    const size_t strideB = (size_t)K_ * 32;
    const _Float16* bptr = eh + (size_t)c0 * 32 + (size_t)((wc * 64 + nl) * 32 + sw8);
    const int aoff = (wr * 64 + nl) * 32 + sw8;

    floatx4 acc[4][4];
    #pragma unroll
    for (int i = 0; i < 4; i++)
        #pragma unroll
        for (int j = 0; j < 4; j++) acc[i][j] = (floatx4)0.f;

    #pragma unroll
    for (int g = 0; g < 2; g++)
        load_lds16(gsrc + g * 512, sA[0] + wid * 2 * 512 + g * 512);

    for (int kb = 0; kb < NKB32; kb++) {
        __syncthreads();   // drains vmcnt: A(kb) landed; buf (kb+1)&1 free

        half8 b_h[4];
        #pragma unroll
        for (int s = 0; s < 4; s++)
            b_h[s] = *(const half8*)(bptr + s * 512);
        if (kb + 1 < NKB32) {
            const _Float16* gk = gsrc + (size_t)(kb + 1) * strideA;
            _Float16* ld = sA[(kb + 1) & 1] + wid * 2 * 512;
            #pragma unroll
            for (int g = 0; g < 2; g++)
                load_lds16(gk + g * 512, ld + g * 512);
        }
        const _Float16* ah = sA[kb & 1] + aoff;
        half8 a_h[4];
        #pragma unroll
        for (int s = 0; s < 4; s++)
            a_h[s] = *(const half8*)(ah + s * 512);
        #pragma unroll
        for (int i = 0; i < 4; i++)
            #pragma unroll
            for (int j = 0; j < 4; j++)
                acc[i][j] = __builtin_amdgcn_mfma_f32_16x16x32_f16(a_h[i], b_h[j], acc[i][j], 0, 0, 0);
        bptr += strideB;
    }

    // epilogue: packed-u32 top-2 per row over this 128-code block
    uint32_t colc[4]; float se4[4];
    #pragma unroll
    for (int sn = 0; sn < 4; sn++) {
        const int cl = wc * 64 + sn * 16 + nl;
        colc[sn] = (uint32_t)cl;          // 7-bit block-local col
        se4[sn]  = sE[cl];
    }
    #pragma unroll
    for (int sm = 0; sm < 4; sm++) {
        #pragma unroll
        for (int reg = 0; reg < 4; reg++) {
            const int rm = wr * 64 + sm * 16 + qd * 4 + reg;
            const float zn = sZn[rm];
            uint32_t k0 = 0xFFFFFFFFu, k1 = 0xFFFFFFFFu;
            #pragma unroll
            for (int sn = 0; sn < 4; sn++) {
                const float v = fmaf(acc[sm][sn][reg], -0.03125f, zn + se4[sn]);
                const uint32_t key = (__float_as_uint(v) & 0xFFFFFF80u) | colc[sn];
                const uint32_t t1 = umax32(k0, key);
                k1 = umin32(k1, t1);
                k0 = umin32(k0, key);
            }
            #pragma unroll
            for (int msk = 1; msk <= 8; msk <<= 1) {
                const uint32_t o0 = (uint32_t)__shfl_xor((int)k0, msk, 64);
                const uint32_t o1 = (uint32_t)__shfl_xor((int)k1, msk, 64);
                const uint32_t n0 = umin32(k0, o0);
                k1 = umin32(umax32(k0, o0), umin32(k1, o1));
                k0 = n0;
            }
            if (nl == 0) { cK[wc][rm].x = k0; cK[wc][rm].y = k1; }
        }
    }
    __syncthreads();
    if (t < 128) {
        const uint2 a = cK[0][t], b = cK[1][t];
        uint2 r;
        r.x = umin32(a.x, b.x);
        r.y = umin32(umax32(a.x, b.x), umin32(a.y, b.y));
        pK[(size_t)(m0 + t) * NCB + blockIdx.x] = r;
    }
}

// ---------------- kernel 3: refine + gather + loss partials + histogram ----------------
// (round 7's refine logic, WITHOUT the fused finalizer — that cost ~45us)
__global__ __launch_bounds__(256)
void vq_gather_kernel(const float* __restrict__ z, const float* __restrict__ cb,
                      const float* __restrict__ znorm, const float* __restrict__ enorm,
                      const uint2* __restrict__ pK,
                      float* __restrict__ out_zq, float* __restrict__ out_idx,
                      int* __restrict__ counts, float* __restrict__ blockLoss) {
    const int lane = threadIdx.x & 63, wid = threadIdx.x >> 6;
    const int m = blockIdx.x * 4 + wid;

    uint32_t k0 = 0xFFFFFFFFu, k1 = 0xFFFFFFFFu;
    if (lane < NCB) {
        const uint2 kk = pK[(size_t)m * NCB + lane];
        k0 = kk.x; k1 = kk.y;
    }
    uint32_t g = k0;
    #pragma unroll
    for (int msk = 1; msk < 64; msk <<= 1) {
        const uint32_t o = (uint32_t)__shfl_xor((int)g, msk, 64);
        g = umin32(g, o);
    }
    const float gvf = __uint_as_float(g & 0xFFFFFF80u) + MARGIN;
    const bool f0 = (lane < NCB) && (__uint_as_float(k0 & 0xFFFFFF80u) <= gvf);
    const bool f1 = (lane < NCB) && (__uint_as_float(k1 & 0xFFFFFF80u) <= gvf);
    const unsigned long long b0 = __ballot(f0), b1 = __ballot(f1);
    int idx;
    if (__popcll(b0) + __popcll(b1) <= 1) {
        const unsigned long long bw = __ballot(k0 == g);
        idx = (int)__builtin_ctzll(bw) * 128 + (int)(g & 0x7Fu);
    } else {
        // exact fp32-lattice distance per candidate: d = fp32(fp32(zn+en) - 2*dot)
        const float zn = znorm[m];
        const float* zrow = z + (size_t)m * D_;
        float bestd = 1e30f; int besti = 0x7fffffff;
        #pragma unroll
        for (int slot = 0; slot < 2; slot++) {
            unsigned long long bm = slot ? b1 : b0;
            while (bm) {
                const int l = (int)__builtin_ctzll(bm); bm &= bm - 1;
                const uint32_t kx = (uint32_t)__shfl((int)(slot ? k1 : k0), l, 64);
                const int cand = l * 128 + (int)(kx & 0x7Fu);
                const float* crow = cb + (size_t)cand * D_;
                float s = 0.f;
                #pragma unroll
                for (int j = 0; j < 8; j++)
                    s += zrow[lane * 8 + j] * crow[lane * 8 + j];
                #pragma unroll
                for (int msk = 1; msk < 64; msk <<= 1) s += __shfl_xor(s, msk, 64);
                const float d = (zn + enorm[cand]) - 2.0f * s;
                if (lexlt(d, cand, bestd, besti)) { bestd = d; besti = cand; }
            }
        }
        idx = besti;
    }

    const float4* qrow  = (const float4*)(cb + (size_t)idx * D_);
    const float4* zrow4 = (const float4*)(z + (size_t)m * D_);
    float4*       orow  = (float4*)(out_zq + (size_t)m * D_);
    float lsum = 0.f;
    #pragma unroll
    for (int i = 0; i < 2; i++) {
        const int j = lane + i * 64;
        const float4 q  = qrow[j];
        const float4 zv = zrow4[j];
        float4 o;
        o.x = zv.x + (q.x - zv.x); o.y = zv.y + (q.y - zv.y);
        o.z = zv.z + (q.z - zv.z); o.w = zv.w + (q.w - zv.w);
        orow[j] = o;
        const float dx = zv.x - q.x, dy = zv.y - q.y, dz = zv.z - q.z, dw = zv.w - q.w;
        lsum += dx * dx + dy * dy + dz * dz + dw * dw;
    }
    #pragma unroll
    for (int msk = 1; msk < 64; msk <<= 1) lsum += __shfl_xor(lsum, msk, 64);

    if (lane == 0) {
        out_idx[m] = (float)idx;
        atomicAdd(&counts[idx], 1);
    }
    __shared__ float wl[4];
    if (lane == 0) wl[wid] = lsum;
    __syncthreads();
    if (threadIdx.x == 0) blockLoss[blockIdx.x] = wl[0] + wl[1] + wl[2] + wl[3];
}

// ---------------- kernel 4: scalars (loss, perplexity) ----------------
__global__ void vq_final_kernel(const int* __restrict__ counts,
                                const float* __restrict__ blockLoss,
                                float* __restrict__ out_loss, float* __restrict__ out_ppl) {
    __shared__ float sl[256], se[256];
    const int t = threadIdx.x;
    float ls = 0.f, es = 0.f;
    for (int i = t; i < N_ / 4; i += 256) ls += blockLoss[i];
    for (int k = t; k < K_; k += 256) {
        const float p = (float)counts[k] / (float)N_;
        es += p * logf(p + 1e-10f);
    }
    sl[t] = ls; se[t] = es;
    __syncthreads();
    for (int s = 128; s > 0; s >>= 1) {
        if (t < s) { sl[t] += sl[t + s]; se[t] += se[t + s]; }
        __syncthreads();
    }
    if (t == 0) {
        out_loss[0] = 0.25f * (sl[0] / (float)((size_t)N_ * D_));
        out_ppl[0]  = expf(-se[0]);
    }
}

extern "C" void kernel_launch(void* const* d_in, const int* in_sizes, int n_in,
                              void* d_out, int out_size, void* d_ws, size_t ws_size,
                              hipStream_t stream) {
    const float* z  = (const float*)d_in[0];
    const float* cb = (const float*)d_in[1];
    float* out = (float*)d_out;

    char* ws = (char*)d_ws;
    uint2*    pK        = (uint2*)   (ws + OFF_PK);
    float*    enorm     = (float*)   (ws + OFF_EN);
    float*    znorm     = (float*)   (ws + OFF_ZN);
    int*      counts    = (int*)     (ws + OFF_CNT);
    float*    blockLoss = (float*)   (ws + OFF_BL);
    _Float16* zh        = (_Float16*)(ws + OFF_ZH);
    _Float16* eh        = (_Float16*)(ws + OFF_EH);

    float* out_zq   = out;                         // [N_*D_]
    float* out_loss = out + (size_t)N_ * D_;       // [1]
    float* out_idx  = out_loss + 1;                // [N_]
    float* out_ppl  = out_idx + N_;                // [1]

    vq_prep_kernel<<<(N_ + K_) * 64 / 256, 256, 0, stream>>>(z, cb, zh, eh,
                                                             znorm, enorm, counts);

    dim3 grid(K_ / 128, N_ / 128);   // x = c-block fast: eh L2-resident
    vq_dist_kernel<<<grid, 256, 0, stream>>>(zh, eh, enorm, znorm, pK);

    vq_gather_kernel<<<N_ / 4, 256, 0, stream>>>(z, cb, znorm, enorm, pK,
                                                 out_zq, out_idx, counts, blockLoss);

    vq_final_kernel<<<1, 256, 0, stream>>>(counts, blockLoss, out_loss, out_ppl);
}